// Round 5
// baseline (1310.219 us; speedup 1.0000x reference)
//
#include <hip/hip_runtime.h>
#include <hip/hip_fp16.h>

#define NBUS 118
#define BATCH 4096
#define NN (BATCH * NBUS)          // 483328 nodes
#define END_E (4 * NN)             // 1933312 no-diag edges
#define EF_E (END_E + NN)          // 2416640 full edges
#define NLAYERS 10

#define NBKT 236                   // coarse dst buckets, span 2048: 236*2048 == NN
#define SPAN_SHIFT 11
#define SPAN_MASK 2047
#define TILE 4096                  // edges per binA block
#define ND_TILES (END_E / TILE)    // 472 (exact)
#define F_TILES  (EF_E / TILE)     // 590 (exact)
#define CAP_ND 8960                // avg 8192 per bucket, +8.5 sigma pad
#define CAP_F  11008               // avg 10240 per bucket, +7.6 sigma pad

#define W_ND 8                     // ELL width (slot W-1 doubles as tail descriptor)
#define W_F 9
#define TAILCAP 1048576            // 2^20 entries per tail array (expected ~40-60K)
#define SLAB 512                   // nodes per LDS ELL slab (4 slabs per bucket)

// ---------- K1: p, denomInv, cursors, err slots ----------
__global__ void init_kernel(const float* __restrict__ x,
                            const float* __restrict__ ybus,
                            float* __restrict__ p,
                            float* __restrict__ denomInv,
                            int* __restrict__ cursor_nd,
                            int* __restrict__ cursor_f,
                            int* __restrict__ tailCur,
                            float* __restrict__ errOut) {
    int tid = blockIdx.x * blockDim.x + threadIdx.x;
    int stride = gridDim.x * blockDim.x;
    for (int i = tid; i < NN; i += stride) {
        float2 xi = ((const float2*)x)[i];
        p[i] = xi.x - xi.y;
        int b = i / NBUS;
        int j = i - b * NBUS;
        denomInv[i] = 1.0f / (ybus[b * (NBUS * NBUS) + j * (NBUS + 1)] * 100.0f);
    }
    if (tid < 256) {
        cursor_nd[tid] = tid * CAP_ND;
        cursor_f[tid]  = tid * CAP_F;
    }
    if (tid < 2) tailCur[tid] = 0;
    if (tid < NLAYERS + 1) errOut[tid] = 0.0f;
}

// ---------- K2 (binA): tile -> LDS bin by coarse bucket -> chunked staging writes ----------
// staged entry: .x = src | (dstLocal<<19), .y = bits(w*100)
__global__ __launch_bounds__(256) void binA_kernel(
        const int* __restrict__ src_nd, const int* __restrict__ dst_nd,
        const float* __restrict__ ea_nd,
        const int* __restrict__ src_f, const int* __restrict__ dst_f,
        const float* __restrict__ ea_f,
        int* __restrict__ cursor_nd, int* __restrict__ cursor_f,
        uint2* __restrict__ stg_nd, uint2* __restrict__ stg_f) {
    __shared__ uint2 buf[TILE];            // 32 KB
    __shared__ unsigned char sb[TILE];     // 4 KB
    __shared__ int hist[256];
    __shared__ int scanA[256];
    __shared__ int segStart[256];
    __shared__ int segGBase[256];

    bool isF = blockIdx.x >= ND_TILES;
    int tile = isF ? (blockIdx.x - ND_TILES) : blockIdx.x;
    const int* src = isF ? src_f : src_nd;
    const int* dst = isF ? dst_f : dst_nd;
    const float* ea = isF ? ea_f : ea_nd;
    int* cursor = isF ? cursor_f : cursor_nd;
    uint2* stg = isF ? stg_f : stg_nd;
    int cap = isF ? CAP_F : CAP_ND;

    int tid = threadIdx.x;
    int base = tile * TILE;

    hist[tid] = 0;
    __syncthreads();

    #pragma unroll
    for (int k = 0; k < TILE / 256; ++k) {
        int d = dst[base + k * 256 + tid];
        atomicAdd(&hist[d >> SPAN_SHIFT], 1);
    }
    __syncthreads();

    int cnt = hist[tid];
    scanA[tid] = cnt;
    __syncthreads();
    for (int off = 1; off < 256; off <<= 1) {
        int t = (tid >= off) ? scanA[tid - off] : 0;
        __syncthreads();
        scanA[tid] += t;
        __syncthreads();
    }
    int excl = scanA[tid] - cnt;
    segStart[tid] = excl;
    hist[tid] = excl;
    if (tid < NBKT && cnt > 0) segGBase[tid] = atomicAdd(&cursor[tid], cnt);
    __syncthreads();

    #pragma unroll
    for (int k = 0; k < TILE / 256; ++k) {
        int e = base + k * 256 + tid;
        int d = dst[e];
        int bkt = d >> SPAN_SHIFT;
        int pos = atomicAdd(&hist[bkt], 1);
        unsigned dl = (unsigned)(d & SPAN_MASK);
        buf[pos] = make_uint2((unsigned)src[e] | (dl << 19),
                              (unsigned)__float_as_int(ea[e] * 100.0f));
        sb[pos] = (unsigned char)bkt;
    }
    __syncthreads();

    #pragma unroll
    for (int k = 0; k < TILE / 256; ++k) {
        int slot = k * 256 + tid;
        int bkt = sb[slot];
        int gpos = segGBase[bkt] + (slot - segStart[bkt]);
        if (gpos < (bkt + 1) * cap)  // freak-overflow guard
            stg[gpos] = buf[slot];
    }
}

// ---------- K3 (binB): per-bucket ELL build via LDS slabs, coalesced flush ----------
// ELL layout: ellSrc[s*NN + node] (int), ellW[s*NN + node] (f16).
// Slot W-1 descriptor for rows with count>W: sign bit | len<<20 | tailBase.
__global__ __launch_bounds__(256) void binB_kernel(
        const uint2* __restrict__ stg_nd, const uint2* __restrict__ stg_f,
        const int* __restrict__ cursor_nd, const int* __restrict__ cursor_f,
        int* __restrict__ ellSrcND, __half* __restrict__ ellWND,
        int* __restrict__ ellSrcF, __half* __restrict__ ellWF,
        int2* __restrict__ tailND, int2* __restrict__ tailF,
        int* __restrict__ tailCur /* [0]=nd [1]=f */) {
    __shared__ int h[2048];                  // per-local-node count
    __shared__ int rk[2048];                 // per-local-node rank cursor
    __shared__ int tb[2048];                 // tail base (-1 = guard-dropped)
    __shared__ int srcSlab[W_F * SLAB];      // 18 KB
    __shared__ unsigned short wSlab[W_F * SLAB]; // 9 KB

    bool isF = blockIdx.x >= NBKT;
    int bb = isF ? (blockIdx.x - NBKT) : blockIdx.x;
    const uint2* stg = isF ? stg_f : stg_nd;
    int cap = isF ? CAP_F : CAP_ND;
    int W = isF ? W_F : W_ND;
    int* ellSrc = isF ? ellSrcF : ellSrcND;
    __half* ellW = isF ? ellWF : ellWND;
    int2* tail = isF ? tailF : tailND;
    int* tc = isF ? (tailCur + 1) : tailCur;
    int cnt = (isF ? cursor_f[bb] : cursor_nd[bb]) - bb * cap;
    if (cnt > cap) cnt = cap;
    int stgBase = bb * cap;
    int nodeBase = bb * 2048;
    int tid = threadIdx.x;

    #pragma unroll
    for (int k = 0; k < 8; ++k) { h[k * 256 + tid] = 0; rk[k * 256 + tid] = 0; }
    __syncthreads();

    // phase 1: per-node histogram
    for (int i = tid; i < cnt; i += 256) {
        uint2 v = stg[stgBase + i];
        atomicAdd(&h[(v.x >> 19) & SPAN_MASK], 1);
    }
    __syncthreads();

    // phase 2: tail allocation for overflow rows (count > W)
    #pragma unroll
    for (int k = 0; k < 8; ++k) {
        int dl = k * 256 + tid;
        int c = h[dl];
        if (c > W) {
            int len = c - (W - 1);
            int tbase = atomicAdd(tc, len);
            tb[dl] = (tbase + len > TAILCAP) ? -1 : tbase;  // freak guard
        }
    }
    __syncthreads();

    // phase 3: four 512-node slab passes
    const int nvec = W * (SLAB / 4);   // int4 / ushort4 count per slab
    for (int pslab = 0; pslab < 2048 / SLAB; ++pslab) {
        // 3a: zero slab
        for (int idx = tid; idx < nvec; idx += 256) {
            ((int4*)srcSlab)[idx] = make_int4(0, 0, 0, 0);
            ((ushort4*)wSlab)[idx] = make_ushort4(0, 0, 0, 0);
        }
        __syncthreads();
        // 3b: descriptors for overflow rows in this slab
        for (int l = tid; l < SLAB; l += 256) {
            int dl = pslab * SLAB + l;
            int c = h[dl];
            if (c > W) {
                int tbase = tb[dl];
                unsigned len = (tbase < 0) ? 0u : (unsigned)(c - (W - 1));
                if (len > 2047u) len = 2047u;
                unsigned tb_enc = (tbase < 0) ? 0u : (unsigned)tbase;
                srcSlab[(W - 1) * SLAB + l] = (int)(0x80000000u | (len << 20) | tb_enc);
            }
        }
        __syncthreads();
        // 3c: scatter staged entries belonging to this slab
        for (int i = tid; i < cnt; i += 256) {
            uint2 v = stg[stgBase + i];
            int dl = (v.x >> 19) & SPAN_MASK;
            if ((dl >> 9) != pslab) continue;
            int l = dl & (SLAB - 1);
            int c = h[dl];
            int r = atomicAdd(&rk[dl], 1);
            int plain = (c <= W) ? c : (W - 1);
            if (r < plain) {
                srcSlab[r * SLAB + l] = (int)(v.x & 0x7FFFF);
                wSlab[r * SLAB + l] = __half_as_ushort(__float2half(__int_as_float(v.y)));
            } else if (tb[dl] >= 0) {
                int pos = tb[dl] + r - plain;
                if (pos < TAILCAP)
                    tail[pos] = make_int2((int)(v.x & 0x7FFFF), (int)v.y);
            }
        }
        __syncthreads();
        // 3d: coalesced flush (src as int4, w as ushort4)
        int gbase = nodeBase + pslab * SLAB;
        for (int idx = tid; idx < nvec; idx += 256) {
            int row = idx >> 7;          // SLAB/4 = 128 vectors per row
            int col = idx & 127;
            ((int4*)(ellSrc + row * NN + gbase))[col] = ((int4*)srcSlab)[idx];
            ((ushort4*)(ellW + row * NN + gbase))[col] = ((ushort4*)wSlab)[idx];
        }
        __syncthreads();
    }
}

// ---------- K4: layer 0 (theta = 0): out0 = p*denomInv - slack ----------
__global__ void out0_kernel(const float* __restrict__ p,
                            const float* __restrict__ denomInv,
                            float* __restrict__ out) {
    int b = blockIdx.x;
    int j = threadIdx.x;
    int i = b * NBUS + j;
    __shared__ float z0;
    float z = 0.0f;
    if (j < NBUS) z = p[i] * denomInv[i];
    if (j == 0) z0 = z;
    __syncthreads();
    if (j < NBUS) out[i] = z - z0;
}

// ---------- K5: fused layer: ELL gather nd -> out_k ; ELL gather f -> err_{k-1} ----------
template <bool DO_OUT>
__global__ __launch_bounds__(128) void layer_kernel(
        const int* __restrict__ ellSrcND, const __half* __restrict__ ellWND,
        const int2* __restrict__ tailND,
        const int* __restrict__ ellSrcF, const __half* __restrict__ ellWF,
        const int2* __restrict__ tailF,
        const float* __restrict__ cur,
        const float* __restrict__ p,
        const float* __restrict__ denomInv,
        float* __restrict__ out,
        float* __restrict__ errSlot) {
    int b = blockIdx.x;
    int j = threadIdx.x;
    int i = b * NBUS + j;
    bool act = j < NBUS;
    __shared__ float z0;
    __shared__ float ws2[2];

    float pv = 0.0f, di = 0.0f;
    float sum_nd = 0.0f, sum_f = 0.0f;
    if (act) {
        pv = p[i];
        if (DO_OUT) {
            di = denomInv[i];
            int sN[W_ND - 1];
            __half wN[W_ND - 1];
            #pragma unroll
            for (int s = 0; s < W_ND - 1; ++s) sN[s] = ellSrcND[s * NN + i];
            #pragma unroll
            for (int s = 0; s < W_ND - 1; ++s) wN[s] = ellWND[s * NN + i];
            #pragma unroll
            for (int s = 0; s < W_ND - 1; ++s)
                sum_nd += cur[sN[s]] * __half2float(wN[s]);
            int last = ellSrcND[(W_ND - 1) * NN + i];
            if (last < 0) {  // tail descriptor
                int len = (last >> 20) & 0x7FF;
                int tbase = last & 0xFFFFF;
                for (int t = 0; t < len; ++t) {
                    int2 pr = tailND[tbase + t];
                    sum_nd += cur[pr.x] * __int_as_float(pr.y);
                }
            } else {
                sum_nd += cur[last] * __half2float(ellWND[(W_ND - 1) * NN + i]);
            }
        }
        {
            int sF[W_F - 1];
            __half wF[W_F - 1];
            #pragma unroll
            for (int s = 0; s < W_F - 1; ++s) sF[s] = ellSrcF[s * NN + i];
            #pragma unroll
            for (int s = 0; s < W_F - 1; ++s) wF[s] = ellWF[s * NN + i];
            #pragma unroll
            for (int s = 0; s < W_F - 1; ++s)
                sum_f += cur[sF[s]] * __half2float(wF[s]);
            int last = ellSrcF[(W_F - 1) * NN + i];
            if (last < 0) {
                int len = (last >> 20) & 0x7FF;
                int tbase = last & 0xFFFFF;
                for (int t = 0; t < len; ++t) {
                    int2 pr = tailF[tbase + t];
                    sum_f += cur[pr.x] * __int_as_float(pr.y);
                }
            } else {
                sum_f += cur[last] * __half2float(ellWF[(W_F - 1) * NN + i]);
            }
        }
    }
    if (DO_OUT) {
        float z = (pv - sum_nd) * di;
        if (j == 0) z0 = z;
        __syncthreads();
        if (act) out[i] = z - z0;
    }
    float acc = act ? fabsf(pv - sum_f) : 0.0f;
    for (int off = 32; off > 0; off >>= 1) acc += __shfl_down(acc, off, 64);
    if ((threadIdx.x & 63) == 0) ws2[threadIdx.x >> 6] = acc;
    __syncthreads();
    if (threadIdx.x == 0) atomicAdd(errSlot, ws2[0] + ws2[1]);
}

extern "C" void kernel_launch(void* const* d_in, const int* in_sizes, int n_in,
                              void* d_out, int out_size, void* d_ws, size_t ws_size,
                              hipStream_t stream) {
    const float* x     = (const float*)d_in[0];
    const int*   ei_nd = (const int*)d_in[2];
    const float* ea_nd = (const float*)d_in[3];
    const int*   ei    = (const int*)d_in[4];
    const float* ea    = (const float*)d_in[5];
    const float* ybus  = (const float*)d_in[6];

    float* out_f = (float*)d_out;
    float* errs  = out_f + NN;

    // workspace carve (4-byte units; every boundary stays divisible by 4 units
    // -> 16 B alignment holds for int4/ushort4 flushes)
    float*  wsf       = (float*)d_ws;
    float*  p         = wsf;           wsf += NN;
    float*  denomInv  = wsf;           wsf += NN;
    float*  outA      = wsf;           wsf += NN;
    float*  outB      = wsf;           wsf += NN;
    int*    cursor_nd = (int*)wsf;     wsf += 256;
    int*    cursor_f  = (int*)wsf;     wsf += 256;
    int*    tailCur   = (int*)wsf;     wsf += 4;
    int*    ellSrcND  = (int*)wsf;     wsf += (long long)W_ND * NN;
    int*    ellSrcF   = (int*)wsf;     wsf += (long long)W_F * NN;
    __half* ellWND    = (__half*)wsf;  wsf += (long long)W_ND * NN / 2;
    __half* ellWF     = (__half*)wsf;  wsf += (long long)W_F * NN / 2;
    int2*   tailND    = (int2*)wsf;    wsf += 2LL * TAILCAP;
    int2*   tailF     = (int2*)wsf;    wsf += 2LL * TAILCAP;
    uint2*  stg_nd    = (uint2*)wsf;   wsf += 2LL * NBKT * CAP_ND;
    uint2*  stg_f     = (uint2*)wsf;   wsf += 2LL * NBKT * CAP_F;

    const int* src_nd = ei_nd;
    const int* dst_nd = ei_nd + END_E;
    const int* src_f  = ei;
    const int* dst_f  = ei + EF_E;

    // ---- build phase ----
    init_kernel<<<1024, 256, 0, stream>>>(x, ybus, p, denomInv,
                                          cursor_nd, cursor_f, tailCur, errs);
    binA_kernel<<<ND_TILES + F_TILES, 256, 0, stream>>>(
        src_nd, dst_nd, ea_nd, src_f, dst_f, ea,
        cursor_nd, cursor_f, stg_nd, stg_f);
    binB_kernel<<<2 * NBKT, 256, 0, stream>>>(
        stg_nd, stg_f, cursor_nd, cursor_f,
        ellSrcND, ellWND, ellSrcF, ellWF, tailND, tailF, tailCur);

    // ---- iterate phase ----
    out0_kernel<<<BATCH, 128, 0, stream>>>(p, denomInv, outA);
    const float* cur = outA;
    for (int k = 1; k <= NLAYERS; ++k) {
        float* nxt = (k == NLAYERS) ? out_f : ((k & 1) ? outB : outA);
        layer_kernel<true><<<BATCH, 128, 0, stream>>>(
            ellSrcND, ellWND, tailND, ellSrcF, ellWF, tailF,
            cur, p, denomInv, nxt, errs + (k - 1));
        cur = nxt;
    }
    layer_kernel<false><<<BATCH, 128, 0, stream>>>(
        ellSrcND, ellWND, tailND, ellSrcF, ellWF, tailF,
        cur, p, denomInv, nullptr, errs + NLAYERS);
}